// Round 1
// baseline (372.972 us; speedup 1.0000x reference)
//
#include <hip/hip_runtime.h>

#define H_N 28
#define KVH_N 4
#define D_N 128
#define S_N 2048
#define E_N 3584
#define NQKV 4608

typedef unsigned short u16;
typedef __bf16 bf16x8 __attribute__((ext_vector_type(8)));
typedef float f32x4 __attribute__((ext_vector_type(4)));
typedef unsigned short u16x8 __attribute__((ext_vector_type(8)));

typedef __attribute__((address_space(1))) void gvoid_t;
typedef __attribute__((address_space(3))) void lvoid_t;

static __device__ __forceinline__ u16 f2bf(float f) {
  __bf16 h = (__bf16)f;
  return __builtin_bit_cast(unsigned short, h);
}

static __device__ __forceinline__ void gload16(const void* g, void* l) {
  __builtin_amdgcn_global_load_lds((gvoid_t*)g, (lvoid_t*)l, 16, 0, 0);
}

// ---------------- elementwise f32 -> bf16 ----------------
__global__ __launch_bounds__(256) void k_f32_to_bf16(const float* __restrict__ in,
                                                     u16* __restrict__ out, int n8) {
  int i = blockIdx.x * 256 + threadIdx.x;
  if (i >= n8) return;
  const float4* p = (const float4*)in + (size_t)i * 2;
  float4 a = p[0], b = p[1];
  u16x8 r;
  r[0] = f2bf(a.x); r[1] = f2bf(a.y); r[2] = f2bf(a.z); r[3] = f2bf(a.w);
  r[4] = f2bf(b.x); r[5] = f2bf(b.y); r[6] = f2bf(b.z); r[7] = f2bf(b.w);
  *((u16x8*)out + i) = r;
}

// ---------------- transpose f32 [R][C] -> bf16 [C][R] ----------------
__global__ __launch_bounds__(256) void k_transpose_bf16(const float* __restrict__ in,
                                                        u16* __restrict__ out,
                                                        int R, int C) {
  __shared__ float t[64][65];
  int r0 = blockIdx.y * 64, c0 = blockIdx.x * 64;
  int lr = threadIdx.x >> 6, lc = threadIdx.x & 63;
#pragma unroll
  for (int i = 0; i < 64; i += 4)
    t[lr + i][lc] = in[(size_t)(r0 + lr + i) * C + c0 + lc];
  __syncthreads();
#pragma unroll
  for (int i = 0; i < 64; i += 4)
    out[(size_t)(c0 + lr + i) * R + r0 + lc] = f2bf(t[lc][lr + i]);
}

// ---------------- GEMM: C[M,N] = A[M,K](bf16) * Bt[N,K](bf16)^T, f32 out ----------------
#define BM 128
#define BN 128
#define BK 32

__global__ __launch_bounds__(256) void k_gemm_bt(const u16* __restrict__ A,
                                                 const u16* __restrict__ Bt,
                                                 float* __restrict__ Cout,
                                                 int M, int N, int K) {
  __shared__ __align__(16) u16 ldsA[2][BM * BK];
  __shared__ __align__(16) u16 ldsB[2][BN * BK];
  const int m0 = blockIdx.y * BM, n0 = blockIdx.x * BN;
  const int tid = threadIdx.x;
  const int w = tid >> 6, lane = tid & 63;
  const int lr = lane & 15, lh = lane >> 4;
  const int row0 = (w >> 1) * 64, col0 = (w & 1) * 64;

  f32x4 acc[4][4];
  const f32x4 z = {0.f, 0.f, 0.f, 0.f};
#pragma unroll
  for (int i = 0; i < 4; i++)
#pragma unroll
    for (int j = 0; j < 4; j++) acc[i][j] = z;

  const int nk = K / BK;
  auto stage = [&](int buf, int kt) {
#pragma unroll
    for (int j = 0; j < 2; ++j) {
      int cb = j * 256 + w * 64;
      int c = cb + lane;
      int row = c >> 2, kc = c & 3;
      gload16(A + (size_t)(m0 + row) * K + kt * BK + kc * 8, &ldsA[buf][cb * 8]);
      gload16(Bt + (size_t)(n0 + row) * K + kt * BK + kc * 8, &ldsB[buf][cb * 8]);
    }
  };
  stage(0, 0);
  for (int kt = 0; kt < nk; ++kt) {
    int cur = kt & 1;
    if (kt + 1 < nk) stage(cur ^ 1, kt + 1);
    __syncthreads();
    bf16x8 a[4], b[4];
#pragma unroll
    for (int mi = 0; mi < 4; mi++)
      a[mi] = *(const bf16x8*)&ldsA[cur][(row0 + mi * 16 + lr) * BK + lh * 8];
#pragma unroll
    for (int ni = 0; ni < 4; ni++)
      b[ni] = *(const bf16x8*)&ldsB[cur][(col0 + ni * 16 + lr) * BK + lh * 8];
#pragma unroll
    for (int mi = 0; mi < 4; mi++)
#pragma unroll
      for (int ni = 0; ni < 4; ni++)
        acc[mi][ni] = __builtin_amdgcn_mfma_f32_16x16x32_bf16(a[mi], b[ni], acc[mi][ni], 0, 0, 0);
    __syncthreads();
  }
#pragma unroll
  for (int mi = 0; mi < 4; mi++) {
    int row = m0 + row0 + mi * 16 + lh * 4;
#pragma unroll
    for (int ni = 0; ni < 4; ni++) {
      int col = n0 + col0 + ni * 16 + lr;
#pragma unroll
      for (int r = 0; r < 4; r++)
        Cout[(size_t)(row + r) * N + col] = acc[mi][ni][r];
    }
  }
}

// ---------------- bias + RoPE for q,k; writes bf16. K pre-swizzled (d ^= (s&7)<<3) ----------------
__global__ __launch_bounds__(256) void k_postproc(const float* __restrict__ Cq,
                                                  const float* __restrict__ qb,
                                                  const float* __restrict__ kb,
                                                  const float* __restrict__ cosb,
                                                  const float* __restrict__ sinb,
                                                  u16* __restrict__ Qo,
                                                  u16* __restrict__ Ko) {
  int s = blockIdx.x;
  int col = blockIdx.y * 256 + threadIdx.x;  // 0..4095 (q then k)
  int d = col & 127;
  float c = cosb[s * D_N + d], sn = sinb[s * D_N + d];
  const float* row = Cq + (size_t)s * NQKV;
  if (col < E_N) {
    float val = row[col] + qb[col];
    float other = (d < 64) ? -(row[col + 64] + qb[col + 64]) : (row[col - 64] + qb[col - 64]);
    int h = col >> 7;
    Qo[((size_t)h * S_N + s) * D_N + d] = f2bf(val * c + other * sn);
  } else {
    int cc = col - E_N;
    int kvh = cc >> 7;
    float val = row[col] + kb[cc];
    float other = (d < 64) ? -(row[col + 64] + kb[cc + 64]) : (row[col - 64] + kb[cc - 64]);
    int dsw = d ^ ((s & 7) << 3);  // pre-swizzle for bank-conflict-free ds_read_b128
    Ko[((size_t)kvh * S_N + s) * D_N + dsw] = f2bf(val * c + other * sn);
  }
}

// ---------------- V: bias + transpose to [KVH*D][S] bf16, pre-swizzled (s ^= (c&7)<<3) ----------------
__global__ __launch_bounds__(256) void k_vt(const float* __restrict__ Cq,
                                            const float* __restrict__ vb,
                                            u16* __restrict__ Vt) {
  __shared__ float t[64][65];
  int s0 = blockIdx.x * 64, c0 = blockIdx.y * 64;  // c in 0..511 (= kvh*128+d)
  int lr = threadIdx.x >> 6, lc = threadIdx.x & 63;
  float bias = vb[c0 + lc];
#pragma unroll
  for (int i = 0; i < 64; i += 4)
    t[lr + i][lc] = Cq[(size_t)(s0 + lr + i) * NQKV + 4096 + c0 + lc] + bias;
  __syncthreads();
#pragma unroll
  for (int i = 0; i < 64; i += 4) {
    int cc = c0 + lr + i;
    int ssw = lc ^ ((cc & 7) << 3);
    Vt[(size_t)cc * S_N + s0 + ssw] = f2bf(t[lc][lr + i]);
  }
}

// ---------------- flash attention, GQA, causal ----------------
// grid: (32 qtiles, 28 heads), block 256 (4 waves x 16 q-rows)
__global__ __launch_bounds__(256) void k_attn(const u16* __restrict__ Q,
                                              const u16* __restrict__ Kc,
                                              const u16* __restrict__ Vt,
                                              u16* __restrict__ Aout) {
  __shared__ __align__(16) u16 Klds[64 * 128];
  __shared__ __align__(16) u16 Vlds[128 * 64];
  __shared__ __align__(16) u16 Plds[4][16 * 64];
  const int h = blockIdx.y;
  const int kvh = h / 7;  // H/KVH = 7
  const int qt = 31 - blockIdx.x;  // heavy tiles dispatched first
  const int q0 = qt * 64;
  const int tid = threadIdx.x, w = tid >> 6, lane = tid & 63;
  const int lr = lane & 15, lh = lane >> 4;
  const int sw = (lr & 7) << 3;  // swizzle mask (elements) — row&7 == lr&7 for all tiles used

  // Q fragments (B operand of swapped QK^T): rows q0+w*16+lr, k = d
  bf16x8 qf[4];
  {
    const u16* qp = Q + ((size_t)h * S_N + q0 + w * 16 + lr) * D_N + lh * 8;
#pragma unroll
    for (int dc = 0; dc < 4; ++dc) qf[dc] = *(const bf16x8*)(qp + dc * 32);
  }
  f32x4 o[8];
  const f32x4 z = {0.f, 0.f, 0.f, 0.f};
#pragma unroll
  for (int f = 0; f < 8; f++) o[f] = z;
  float mrow = -3.0e38f, lsum = 0.f;
  const float sc = 0.08838834764831845f;  // 1/sqrt(128)
  const int qglob = q0 + w * 16 + lr;

  const int nt = qt + 1;
  for (int t = 0; t < nt; ++t) {
    __syncthreads();  // previous tile's LDS reads done before restage
    // stage K tile [64][128] and Vt tile [128][64] (both 16KB, pre-swizzled in global)
#pragma unroll
    for (int j = 0; j < 4; ++j) {
      int cb = j * 256 + w * 64;
      int c = cb + lane;
      {
        int row = c >> 4, cw = c & 15;
        gload16(Kc + ((size_t)kvh * S_N + t * 64 + row) * D_N + cw * 8, &Klds[cb * 8]);
      }
      {
        int dd = c >> 3, cw = c & 7;
        gload16(Vt + ((size_t)(kvh * D_N + dd)) * S_N + t * 64 + cw * 8, &Vlds[cb * 8]);
      }
    }
    __syncthreads();
    // S^T = K_tile @ Q^T  (A = K rows, B = Q)
    f32x4 sacc[4];
#pragma unroll
    for (int kf = 0; kf < 4; kf++) sacc[kf] = z;
#pragma unroll
    for (int kf = 0; kf < 4; kf++)
#pragma unroll
      for (int dc = 0; dc < 4; dc++) {
        bf16x8 ka = *(const bf16x8*)&Klds[(kf * 16 + lr) * D_N + ((dc * 32 + lh * 8) ^ sw)];
        sacc[kf] = __builtin_amdgcn_mfma_f32_16x16x32_bf16(ka, qf[dc], sacc[kf], 0, 0, 0);
      }
    // online softmax (row = q = lr; kv split across lane groups lh and regs)
    float sv[16];
    float tmax = -3.0e38f;
#pragma unroll
    for (int kf = 0; kf < 4; kf++)
#pragma unroll
      for (int r = 0; r < 4; r++) {
        int kv = t * 64 + kf * 16 + lh * 4 + r;
        float x = (kv <= qglob) ? sacc[kf][r] * sc : -3.0e38f;
        sv[kf * 4 + r] = x;
        tmax = fmaxf(tmax, x);
      }
    tmax = fmaxf(tmax, __shfl_xor(tmax, 16));
    tmax = fmaxf(tmax, __shfl_xor(tmax, 32));
    float mnew = fmaxf(mrow, tmax);
    float p[16], tsum = 0.f;
#pragma unroll
    for (int i = 0; i < 16; i++) {
      p[i] = __expf(sv[i] - mnew);
      tsum += p[i];
    }
    tsum += __shfl_xor(tsum, 16);
    tsum += __shfl_xor(tsum, 32);
    float scl = __expf(mrow - mnew);
    lsum = lsum * scl + tsum;
    mrow = mnew;
    float rs[4];
#pragma unroll
    for (int r = 0; r < 4; r++) rs[r] = __shfl(scl, (lane & 48) | (lh * 4 + r));
#pragma unroll
    for (int f = 0; f < 8; f++)
#pragma unroll
      for (int r = 0; r < 4; r++) o[f][r] *= rs[r];
    // P -> LDS (bf16, swizzled), per-wave region
#pragma unroll
    for (int kf = 0; kf < 4; kf++)
#pragma unroll
      for (int r2 = 0; r2 < 4; r2 += 2) {
        unsigned int pk =
            (unsigned int)f2bf(p[kf * 4 + r2]) | ((unsigned int)f2bf(p[kf * 4 + r2 + 1]) << 16);
        *(unsigned int*)&Plds[w][lr * 64 + ((kf * 16 + lh * 4 + r2) ^ sw)] = pk;
      }
    __syncthreads();
    // PV: O += P @ V  (A = P rows=q, B = Vt cols=d)
#pragma unroll
    for (int f = 0; f < 8; f++)
#pragma unroll
      for (int kc = 0; kc < 2; kc++) {
        bf16x8 pa = *(const bf16x8*)&Plds[w][lr * 64 + ((kc * 32 + lh * 8) ^ sw)];
        bf16x8 vv = *(const bf16x8*)&Vlds[(f * 16 + lr) * 64 + ((kc * 32 + lh * 8) ^ sw)];
        o[f] = __builtin_amdgcn_mfma_f32_16x16x32_bf16(pa, vv, o[f], 0, 0, 0);
      }
  }
  // epilogue: divide by lsum, write bf16 [S][H*D]
  float ri[4];
#pragma unroll
  for (int r = 0; r < 4; r++) ri[r] = 1.0f / __shfl(lsum, (lane & 48) | (lh * 4 + r));
#pragma unroll
  for (int f = 0; f < 8; f++) {
#pragma unroll
    for (int r = 0; r < 4; r++) {
      int qr = q0 + w * 16 + lh * 4 + r;
      Aout[(size_t)qr * E_N + h * D_N + f * 16 + lr] = f2bf(o[f][r] * ri[r]);
    }
  }
}

extern "C" void kernel_launch(void* const* d_in, const int* in_sizes, int n_in,
                              void* d_out, int out_size, void* d_ws, size_t ws_size,
                              hipStream_t stream) {
  const float* hs   = (const float*)d_in[0];
  const float* cosb = (const float*)d_in[1];
  const float* sinb = (const float*)d_in[2];
  // d_in[3] = attn_mask (always causal tril — applied analytically)
  const float* qw = (const float*)d_in[4];
  const float* qb = (const float*)d_in[5];
  const float* kw = (const float*)d_in[6];
  const float* kb = (const float*)d_in[7];
  const float* vw = (const float*)d_in[8];
  const float* vb = (const float*)d_in[9];
  const float* ow = (const float*)d_in[10];
  float* outp = (float*)d_out;

  char* ws = (char*)d_ws;
  u16* hsb    = (u16*)(ws);                                   // 2048x3584 bf16
  u16* wt     = (u16*)(ws + 14680064);                        // 4608x3584 bf16 (later reused for ow^T)
  float* qkv  = (float*)(ws + 14680064 + 33030144);           // 2048x4608 f32
  u16* attn_o = (u16*)qkv;                                    // reuse region after postproc
  char* p2 = ws + 14680064 + 33030144 + 37748736;
  u16* Qb  = (u16*)p2;                                        // [28][2048][128]
  u16* Kb  = (u16*)(p2 + 14680064);                           // [4][2048][128] (swizzled)
  u16* Vtb = (u16*)(p2 + 14680064 + 2097152);                 // [512][2048] (swizzled)

  // 1. hs -> bf16
  k_f32_to_bf16<<<dim3(7340032 / 8 / 256), dim3(256), 0, stream>>>(hs, hsb, 7340032 / 8);
  // 2-4. weight transposes -> wt (q|k|v rows)
  k_transpose_bf16<<<dim3(3584 / 64, 3584 / 64), dim3(256), 0, stream>>>(qw, wt, 3584, 3584);
  k_transpose_bf16<<<dim3(512 / 64, 3584 / 64), dim3(256), 0, stream>>>(kw, wt + (size_t)3584 * 3584, 3584, 512);
  k_transpose_bf16<<<dim3(512 / 64, 3584 / 64), dim3(256), 0, stream>>>(vw, wt + (size_t)4096 * 3584, 3584, 512);
  // 5. QKV GEMM
  k_gemm_bt<<<dim3(4608 / 128, 2048 / 128), dim3(256), 0, stream>>>(hsb, wt, qkv, 2048, 4608, 3584);
  // 6. bias + RoPE -> Q,K bf16
  k_postproc<<<dim3(2048, 16), dim3(256), 0, stream>>>(qkv, qb, kb, cosb, sinb, Qb, Kb);
  // 7. V bias + transpose
  k_vt<<<dim3(32, 8), dim3(256), 0, stream>>>(qkv, vb, Vtb);
  // 8. ow transpose (into wt region — gemm1 already consumed it)
  k_transpose_bf16<<<dim3(3584 / 64, 3584 / 64), dim3(256), 0, stream>>>(ow, wt, 3584, 3584);
  // 9. attention -> attn_o (bf16, aliases qkv region)
  k_attn<<<dim3(32, 28), dim3(256), 0, stream>>>(Qb, Kb, Vtb, attn_o);
  // 10. output projection -> d_out (f32)
  k_gemm_bt<<<dim3(3584 / 128, 2048 / 128), dim3(256), 0, stream>>>(attn_o, wt, outp, 2048, 3584, 3584);
}

// Round 2
// 372.618 us; speedup vs baseline: 1.0010x; 1.0010x over previous
//
#include <hip/hip_runtime.h>

#define H_N 28
#define KVH_N 4
#define D_N 128
#define S_N 2048
#define E_N 3584
#define NQKV 4608

typedef unsigned short u16;
typedef __bf16 bf16x8 __attribute__((ext_vector_type(8)));
typedef float f32x4 __attribute__((ext_vector_type(4)));
typedef unsigned short u16x8 __attribute__((ext_vector_type(8)));

typedef __attribute__((address_space(1))) void gvoid_t;
typedef __attribute__((address_space(3))) void lvoid_t;

static __device__ __forceinline__ u16 f2bf(float f) {
  __bf16 h = (__bf16)f;
  return __builtin_bit_cast(unsigned short, h);
}

static __device__ __forceinline__ void gload16(const void* g, void* l) {
  __builtin_amdgcn_global_load_lds((gvoid_t*)g, (lvoid_t*)l, 16, 0, 0);
}

// ---------------- elementwise f32 -> bf16 ----------------
__global__ __launch_bounds__(256) void k_f32_to_bf16(const float* __restrict__ in,
                                                     u16* __restrict__ out, int n8) {
  int i = blockIdx.x * 256 + threadIdx.x;
  if (i >= n8) return;
  const float4* p = (const float4*)in + (size_t)i * 2;
  float4 a = p[0], b = p[1];
  u16x8 r;
  r[0] = f2bf(a.x); r[1] = f2bf(a.y); r[2] = f2bf(a.z); r[3] = f2bf(a.w);
  r[4] = f2bf(b.x); r[5] = f2bf(b.y); r[6] = f2bf(b.z); r[7] = f2bf(b.w);
  *((u16x8*)out + i) = r;
}

// ---------------- transpose f32 [R][C] -> bf16 [C][R] ----------------
__global__ __launch_bounds__(256) void k_transpose_bf16(const float* __restrict__ in,
                                                        u16* __restrict__ out,
                                                        int R, int C) {
  __shared__ float t[64][65];
  int r0 = blockIdx.y * 64, c0 = blockIdx.x * 64;
  int lr = threadIdx.x >> 6, lc = threadIdx.x & 63;
#pragma unroll
  for (int i = 0; i < 64; i += 4)
    t[lr + i][lc] = in[(size_t)(r0 + lr + i) * C + c0 + lc];
  __syncthreads();
#pragma unroll
  for (int i = 0; i < 64; i += 4)
    out[(size_t)(c0 + lr + i) * R + r0 + lc] = f2bf(t[lc][lr + i]);
}

// ---------------- GEMM: C[M,N] = A[M,K](bf16) * Bt[N,K](bf16)^T, f32 out ----------------
#define BM 128
#define BN 128
#define BK 32

__global__ __launch_bounds__(256) void k_gemm_bt(const u16* __restrict__ A,
                                                 const u16* __restrict__ Bt,
                                                 float* __restrict__ Cout,
                                                 int M, int N, int K) {
  __shared__ __align__(16) u16 ldsA[2][BM * BK];
  __shared__ __align__(16) u16 ldsB[2][BN * BK];
  const int m0 = blockIdx.y * BM, n0 = blockIdx.x * BN;
  const int tid = threadIdx.x;
  const int w = tid >> 6, lane = tid & 63;
  const int lr = lane & 15, lh = lane >> 4;
  const int row0 = (w >> 1) * 64, col0 = (w & 1) * 64;

  f32x4 acc[4][4];
  const f32x4 z = {0.f, 0.f, 0.f, 0.f};
#pragma unroll
  for (int i = 0; i < 4; i++)
#pragma unroll
    for (int j = 0; j < 4; j++) acc[i][j] = z;

  const int nk = K / BK;
  auto stage = [&](int buf, int kt) {
#pragma unroll
    for (int j = 0; j < 2; ++j) {
      int cb = j * 256 + w * 64;
      int c = cb + lane;
      int row = c >> 2, kc = c & 3;
      gload16(A + (size_t)(m0 + row) * K + kt * BK + kc * 8, &ldsA[buf][cb * 8]);
      gload16(Bt + (size_t)(n0 + row) * K + kt * BK + kc * 8, &ldsB[buf][cb * 8]);
    }
  };
  stage(0, 0);
  for (int kt = 0; kt < nk; ++kt) {
    int cur = kt & 1;
    if (kt + 1 < nk) stage(cur ^ 1, kt + 1);
    __syncthreads();
    bf16x8 a[4], b[4];
#pragma unroll
    for (int mi = 0; mi < 4; mi++)
      a[mi] = *(const bf16x8*)&ldsA[cur][(row0 + mi * 16 + lr) * BK + lh * 8];
#pragma unroll
    for (int ni = 0; ni < 4; ni++)
      b[ni] = *(const bf16x8*)&ldsB[cur][(col0 + ni * 16 + lr) * BK + lh * 8];
#pragma unroll
    for (int mi = 0; mi < 4; mi++)
#pragma unroll
      for (int ni = 0; ni < 4; ni++)
        acc[mi][ni] = __builtin_amdgcn_mfma_f32_16x16x32_bf16(a[mi], b[ni], acc[mi][ni], 0, 0, 0);
    __syncthreads();
  }
#pragma unroll
  for (int mi = 0; mi < 4; mi++) {
    int row = m0 + row0 + mi * 16 + lh * 4;
#pragma unroll
    for (int ni = 0; ni < 4; ni++) {
      int col = n0 + col0 + ni * 16 + lr;
#pragma unroll
      for (int r = 0; r < 4; r++)
        Cout[(size_t)(row + r) * N + col] = acc[mi][ni][r];
    }
  }
}

// ---------------- bias + RoPE for q,k; writes bf16. K pre-swizzled (d ^= (s&7)<<3) ----------------
__global__ __launch_bounds__(256) void k_postproc(const float* __restrict__ Cq,
                                                  const float* __restrict__ qb,
                                                  const float* __restrict__ kb,
                                                  const float* __restrict__ cosb,
                                                  const float* __restrict__ sinb,
                                                  u16* __restrict__ Qo,
                                                  u16* __restrict__ Ko) {
  int s = blockIdx.x;
  int col = blockIdx.y * 256 + threadIdx.x;  // 0..4095 (q then k)
  int d = col & 127;
  float c = cosb[s * D_N + d], sn = sinb[s * D_N + d];
  const float* row = Cq + (size_t)s * NQKV;
  if (col < E_N) {
    float val = row[col] + qb[col];
    float other = (d < 64) ? -(row[col + 64] + qb[col + 64]) : (row[col - 64] + qb[col - 64]);
    int h = col >> 7;
    Qo[((size_t)h * S_N + s) * D_N + d] = f2bf(val * c + other * sn);
  } else {
    int cc = col - E_N;
    int kvh = cc >> 7;
    float val = row[col] + kb[cc];
    float other = (d < 64) ? -(row[col + 64] + kb[cc + 64]) : (row[col - 64] + kb[cc - 64]);
    int dsw = d ^ ((s & 7) << 3);  // pre-swizzle for bank-conflict-free ds_read_b128
    Ko[((size_t)kvh * S_N + s) * D_N + dsw] = f2bf(val * c + other * sn);
  }
}

// ---------------- V: bias + transpose to [KVH*D][S] bf16, pre-swizzled (s ^= (c&7)<<3) ----------------
__global__ __launch_bounds__(256) void k_vt(const float* __restrict__ Cq,
                                            const float* __restrict__ vb,
                                            u16* __restrict__ Vt) {
  __shared__ float t[64][65];
  int s0 = blockIdx.x * 64, c0 = blockIdx.y * 64;  // c in 0..511 (= kvh*128+d)
  int lr = threadIdx.x >> 6, lc = threadIdx.x & 63;
  float bias = vb[c0 + lc];
#pragma unroll
  for (int i = 0; i < 64; i += 4)
    t[lr + i][lc] = Cq[(size_t)(s0 + lr + i) * NQKV + 4096 + c0 + lc] + bias;
  __syncthreads();
#pragma unroll
  for (int i = 0; i < 64; i += 4) {
    int cc = c0 + lr + i;
    int ssw = lc ^ ((cc & 7) << 3);
    Vt[(size_t)cc * S_N + s0 + ssw] = f2bf(t[lc][lr + i]);
  }
}

// ---------------- flash attention, GQA, causal ----------------
// grid: (32 qtiles, 28 heads), block 256 (4 waves x 16 q-rows)
// Double-buffered K/V (72KB LDS, 2 blocks/CU); one barrier per KV tile;
// stage(t+1) issued before compute(t) so HBM latency hides under MFMA+softmax.
__global__ __launch_bounds__(256) void k_attn(const u16* __restrict__ Q,
                                              const u16* __restrict__ Kc,
                                              const u16* __restrict__ Vt,
                                              u16* __restrict__ Aout) {
  __shared__ __align__(16) u16 Klds[2][64 * 128];
  __shared__ __align__(16) u16 Vlds[2][128 * 64];
  __shared__ __align__(16) u16 Plds[4][16 * 64];
  const int h = blockIdx.y;
  const int kvh = h / 7;  // H/KVH = 7
  const int qt = 31 - blockIdx.x;  // heavy tiles dispatched first
  const int q0 = qt * 64;
  const int tid = threadIdx.x, w = tid >> 6, lane = tid & 63;
  const int lr = lane & 15, lh = lane >> 4;
  const int sw = (lr & 7) << 3;  // swizzle mask (elements)

  // Q fragments (B operand of swapped QK^T): rows q0+w*16+lr, k = d
  bf16x8 qf[4];
  {
    const u16* qp = Q + ((size_t)h * S_N + q0 + w * 16 + lr) * D_N + lh * 8;
#pragma unroll
    for (int dc = 0; dc < 4; ++dc) qf[dc] = *(const bf16x8*)(qp + dc * 32);
  }
  f32x4 o[8];
  const f32x4 z = {0.f, 0.f, 0.f, 0.f};
#pragma unroll
  for (int f = 0; f < 8; f++) o[f] = z;
  float mrow = -3.0e38f, lsum = 0.f;
  const float sc = 0.08838834764831845f;  // 1/sqrt(128)
  const int qglob = q0 + w * 16 + lr;

  auto stageKV = [&](int buf, int t) {
#pragma unroll
    for (int j = 0; j < 4; ++j) {
      int cb = j * 256 + w * 64;
      int c = cb + lane;
      {
        int row = c >> 4, cw = c & 15;
        gload16(Kc + ((size_t)kvh * S_N + t * 64 + row) * D_N + cw * 8, &Klds[buf][cb * 8]);
      }
      {
        int dd = c >> 3, cw = c & 7;
        gload16(Vt + ((size_t)(kvh * D_N + dd)) * S_N + t * 64 + cw * 8, &Vlds[buf][cb * 8]);
      }
    }
  };

  const int nt = qt + 1;
  stageKV(0, 0);
  __syncthreads();  // waits vmcnt(0): tile 0 resident + visible
  for (int t = 0; t < nt; ++t) {
    const int cur = t & 1;
    // issue next tile's loads NOW — latency hides under this tile's compute
    if (t + 1 < nt) stageKV(cur ^ 1, t + 1);
    // S^T = K_tile @ Q^T  (A = K rows, B = Q)
    f32x4 sacc[4];
#pragma unroll
    for (int kf = 0; kf < 4; kf++) sacc[kf] = z;
    __builtin_amdgcn_s_setprio(1);
#pragma unroll
    for (int kf = 0; kf < 4; kf++)
#pragma unroll
      for (int dc = 0; dc < 4; dc++) {
        bf16x8 ka = *(const bf16x8*)&Klds[cur][(kf * 16 + lr) * D_N + ((dc * 32 + lh * 8) ^ sw)];
        sacc[kf] = __builtin_amdgcn_mfma_f32_16x16x32_bf16(ka, qf[dc], sacc[kf], 0, 0, 0);
      }
    __builtin_amdgcn_s_setprio(0);
    // online softmax (row = q = lr; kv split across lane groups lh and regs)
    float sv[16];
    float tmax = -3.0e38f;
#pragma unroll
    for (int kf = 0; kf < 4; kf++)
#pragma unroll
      for (int r = 0; r < 4; r++) {
        int kv = t * 64 + kf * 16 + lh * 4 + r;
        float x = (kv <= qglob) ? sacc[kf][r] * sc : -3.0e38f;
        sv[kf * 4 + r] = x;
        tmax = fmaxf(tmax, x);
      }
    tmax = fmaxf(tmax, __shfl_xor(tmax, 16));
    tmax = fmaxf(tmax, __shfl_xor(tmax, 32));
    float mnew = fmaxf(mrow, tmax);
    float p[16], tsum = 0.f;
#pragma unroll
    for (int i = 0; i < 16; i++) {
      p[i] = __expf(sv[i] - mnew);
      tsum += p[i];
    }
    tsum += __shfl_xor(tsum, 16);
    tsum += __shfl_xor(tsum, 32);
    float scl = __expf(mrow - mnew);
    lsum = lsum * scl + tsum;
    mrow = mnew;
    float rs[4];
#pragma unroll
    for (int r = 0; r < 4; r++) rs[r] = __shfl(scl, (lane & 48) | (lh * 4 + r));
#pragma unroll
    for (int f = 0; f < 8; f++)
#pragma unroll
      for (int r = 0; r < 4; r++) o[f][r] *= rs[r];
    // P -> LDS (bf16, swizzled). Per-wave region: written AND read only by
    // this wave -> no barrier needed (intra-wave lgkmcnt ordering suffices).
#pragma unroll
    for (int kf = 0; kf < 4; kf++)
#pragma unroll
      for (int r2 = 0; r2 < 4; r2 += 2) {
        unsigned int pk =
            (unsigned int)f2bf(p[kf * 4 + r2]) | ((unsigned int)f2bf(p[kf * 4 + r2 + 1]) << 16);
        *(unsigned int*)&Plds[w][lr * 64 + ((kf * 16 + lh * 4 + r2) ^ sw)] = pk;
      }
    // PV: O += P @ V  (A = P rows=q, B = Vt cols=d)
    __builtin_amdgcn_s_setprio(1);
#pragma unroll
    for (int f = 0; f < 8; f++)
#pragma unroll
      for (int kc = 0; kc < 2; kc++) {
        bf16x8 pa = *(const bf16x8*)&Plds[w][lr * 64 + ((kc * 32 + lh * 8) ^ sw)];
        bf16x8 vv = *(const bf16x8*)&Vlds[cur][(f * 16 + lr) * 64 + ((kc * 32 + lh * 8) ^ sw)];
        o[f] = __builtin_amdgcn_mfma_f32_16x16x32_bf16(pa, vv, o[f], 0, 0, 0);
      }
    __builtin_amdgcn_s_setprio(0);
    // single barrier per tile: waits vmcnt(0) (next tile staged) + all waves
    // done reading buf `cur` (safe to overwrite next iteration)
    __syncthreads();
  }
  // epilogue: divide by lsum, write bf16 [S][H*D]
  float ri[4];
#pragma unroll
  for (int r = 0; r < 4; r++) ri[r] = 1.0f / __shfl(lsum, (lane & 48) | (lh * 4 + r));
#pragma unroll
  for (int f = 0; f < 8; f++) {
#pragma unroll
    for (int r = 0; r < 4; r++) {
      int qr = q0 + w * 16 + lh * 4 + r;
      Aout[(size_t)qr * E_N + h * D_N + f * 16 + lr] = f2bf(o[f][r] * ri[r]);
    }
  }
}

extern "C" void kernel_launch(void* const* d_in, const int* in_sizes, int n_in,
                              void* d_out, int out_size, void* d_ws, size_t ws_size,
                              hipStream_t stream) {
  const float* hs   = (const float*)d_in[0];
  const float* cosb = (const float*)d_in[1];
  const float* sinb = (const float*)d_in[2];
  // d_in[3] = attn_mask (always causal tril — applied analytically)
  const float* qw = (const float*)d_in[4];
  const float* qb = (const float*)d_in[5];
  const float* kw = (const float*)d_in[6];
  const float* kb = (const float*)d_in[7];
  const float* vw = (const float*)d_in[8];
  const float* vb = (const float*)d_in[9];
  const float* ow = (const float*)d_in[10];
  float* outp = (float*)d_out;

  char* ws = (char*)d_ws;
  u16* hsb    = (u16*)(ws);                                   // 2048x3584 bf16
  u16* wt     = (u16*)(ws + 14680064);                        // 4608x3584 bf16 (later reused for ow^T)
  float* qkv  = (float*)(ws + 14680064 + 33030144);           // 2048x4608 f32
  u16* attn_o = (u16*)qkv;                                    // reuse region after postproc
  char* p2 = ws + 14680064 + 33030144 + 37748736;
  u16* Qb  = (u16*)p2;                                        // [28][2048][128]
  u16* Kb  = (u16*)(p2 + 14680064);                           // [4][2048][128] (swizzled)
  u16* Vtb = (u16*)(p2 + 14680064 + 2097152);                 // [512][2048] (swizzled)

  // 1. hs -> bf16
  k_f32_to_bf16<<<dim3(7340032 / 8 / 256), dim3(256), 0, stream>>>(hs, hsb, 7340032 / 8);
  // 2-4. weight transposes -> wt (q|k|v rows)
  k_transpose_bf16<<<dim3(3584 / 64, 3584 / 64), dim3(256), 0, stream>>>(qw, wt, 3584, 3584);
  k_transpose_bf16<<<dim3(512 / 64, 3584 / 64), dim3(256), 0, stream>>>(kw, wt + (size_t)3584 * 3584, 3584, 512);
  k_transpose_bf16<<<dim3(512 / 64, 3584 / 64), dim3(256), 0, stream>>>(vw, wt + (size_t)4096 * 3584, 3584, 512);
  // 5. QKV GEMM
  k_gemm_bt<<<dim3(4608 / 128, 2048 / 128), dim3(256), 0, stream>>>(hsb, wt, qkv, 2048, 4608, 3584);
  // 6. bias + RoPE -> Q,K bf16
  k_postproc<<<dim3(2048, 16), dim3(256), 0, stream>>>(qkv, qb, kb, cosb, sinb, Qb, Kb);
  // 7. V bias + transpose
  k_vt<<<dim3(32, 8), dim3(256), 0, stream>>>(qkv, vb, Vtb);
  // 8. ow transpose (into wt region — gemm1 already consumed it)
  k_transpose_bf16<<<dim3(3584 / 64, 3584 / 64), dim3(256), 0, stream>>>(ow, wt, 3584, 3584);
  // 9. attention -> attn_o (bf16, aliases qkv region)
  k_attn<<<dim3(32, 28), dim3(256), 0, stream>>>(Qb, Kb, Vtb, attn_o);
  // 10. output projection -> d_out (f32)
  k_gemm_bt<<<dim3(3584 / 128, 2048 / 128), dim3(256), 0, stream>>>(attn_o, wt, outp, 2048, 3584, 3584);
}

// Round 3
// 311.481 us; speedup vs baseline: 1.1974x; 1.1963x over previous
//
#include <hip/hip_runtime.h>

#define H_N 28
#define KVH_N 4
#define D_N 128
#define S_N 2048
#define E_N 3584
#define NQKV 4608

typedef unsigned short u16;
typedef unsigned int u32;
typedef __bf16 bf16x8 __attribute__((ext_vector_type(8)));
typedef float f32x4 __attribute__((ext_vector_type(4)));
typedef float f32x16 __attribute__((ext_vector_type(16)));
typedef unsigned short u16x8 __attribute__((ext_vector_type(8)));
typedef unsigned int u32x2 __attribute__((ext_vector_type(2)));
typedef unsigned int u32x4 __attribute__((ext_vector_type(4)));

typedef __attribute__((address_space(1))) void gvoid_t;
typedef __attribute__((address_space(3))) void lvoid_t;

static __device__ __forceinline__ u16 f2bf(float f) {
  __bf16 h = (__bf16)f;
  return __builtin_bit_cast(unsigned short, h);
}

static __device__ __forceinline__ void gload16(const void* g, void* l) {
  __builtin_amdgcn_global_load_lds((gvoid_t*)g, (lvoid_t*)l, 16, 0, 0);
}

static __device__ __forceinline__ u32 cvt_pk_bf16(float lo, float hi) {
  u32 r;
  asm("v_cvt_pk_bf16_f32 %0, %1, %2" : "=v"(r) : "v"(lo), "v"(hi));
  return r;
}

// v_permlane32_swap_b32 a, b : a.hi <-> b.lo
// after: a = [a_lo | b_from(lane-32)], b = [a_from(lane+32) | b_hi]
static __device__ __forceinline__ void pl32swap(u32& a, u32& b) {
  asm volatile("v_permlane32_swap_b32 %0, %1" : "+v"(a), "+v"(b));
}

static __device__ __forceinline__ float vmax16(f32x16 v) {
  float a = fmaxf(fmaxf(v[0], v[1]), fmaxf(v[2], v[3]));
  float b = fmaxf(fmaxf(v[4], v[5]), fmaxf(v[6], v[7]));
  float c = fmaxf(fmaxf(v[8], v[9]), fmaxf(v[10], v[11]));
  float d = fmaxf(fmaxf(v[12], v[13]), fmaxf(v[14], v[15]));
  return fmaxf(fmaxf(a, b), fmaxf(c, d));
}

static __device__ __forceinline__ float vsum16(f32x16 v) {
  float a = (v[0] + v[1]) + (v[2] + v[3]);
  float b = (v[4] + v[5]) + (v[6] + v[7]);
  float c = (v[8] + v[9]) + (v[10] + v[11]);
  float d = (v[12] + v[13]) + (v[14] + v[15]);
  return (a + b) + (c + d);
}

// ---------------- elementwise f32 -> bf16 ----------------
__global__ __launch_bounds__(256) void k_f32_to_bf16(const float* __restrict__ in,
                                                     u16* __restrict__ out, int n8) {
  int i = blockIdx.x * 256 + threadIdx.x;
  if (i >= n8) return;
  const float4* p = (const float4*)in + (size_t)i * 2;
  float4 a = p[0], b = p[1];
  u16x8 r;
  r[0] = f2bf(a.x); r[1] = f2bf(a.y); r[2] = f2bf(a.z); r[3] = f2bf(a.w);
  r[4] = f2bf(b.x); r[5] = f2bf(b.y); r[6] = f2bf(b.z); r[7] = f2bf(b.w);
  *((u16x8*)out + i) = r;
}

// ---------------- transpose f32 [R][C] -> bf16 [C][R] ----------------
__global__ __launch_bounds__(256) void k_transpose_bf16(const float* __restrict__ in,
                                                        u16* __restrict__ out,
                                                        int R, int C) {
  __shared__ float t[64][65];
  int r0 = blockIdx.y * 64, c0 = blockIdx.x * 64;
  int lr = threadIdx.x >> 6, lc = threadIdx.x & 63;
#pragma unroll
  for (int i = 0; i < 64; i += 4)
    t[lr + i][lc] = in[(size_t)(r0 + lr + i) * C + c0 + lc];
  __syncthreads();
#pragma unroll
  for (int i = 0; i < 64; i += 4)
    out[(size_t)(c0 + lr + i) * R + r0 + lc] = f2bf(t[lc][lr + i]);
}

// ---------------- GEMM: C[M,N] = A[M,K](bf16) * Bt[N,K](bf16)^T, f32 out ----------------
#define BM 128
#define BN 128
#define BK 32

__global__ __launch_bounds__(256) void k_gemm_bt(const u16* __restrict__ A,
                                                 const u16* __restrict__ Bt,
                                                 float* __restrict__ Cout,
                                                 int M, int N, int K) {
  __shared__ __align__(16) u16 ldsA[2][BM * BK];
  __shared__ __align__(16) u16 ldsB[2][BN * BK];
  const int m0 = blockIdx.y * BM, n0 = blockIdx.x * BN;
  const int tid = threadIdx.x;
  const int w = tid >> 6, lane = tid & 63;
  const int lr = lane & 15, lh = lane >> 4;
  const int row0 = (w >> 1) * 64, col0 = (w & 1) * 64;

  f32x4 acc[4][4];
  const f32x4 z = {0.f, 0.f, 0.f, 0.f};
#pragma unroll
  for (int i = 0; i < 4; i++)
#pragma unroll
    for (int j = 0; j < 4; j++) acc[i][j] = z;

  const int nk = K / BK;
  auto stage = [&](int buf, int kt) {
#pragma unroll
    for (int j = 0; j < 2; ++j) {
      int cb = j * 256 + w * 64;
      int c = cb + lane;
      int row = c >> 2, kc = c & 3;
      gload16(A + (size_t)(m0 + row) * K + kt * BK + kc * 8, &ldsA[buf][cb * 8]);
      gload16(Bt + (size_t)(n0 + row) * K + kt * BK + kc * 8, &ldsB[buf][cb * 8]);
    }
  };
  stage(0, 0);
  for (int kt = 0; kt < nk; ++kt) {
    int cur = kt & 1;
    if (kt + 1 < nk) stage(cur ^ 1, kt + 1);
    __syncthreads();
    bf16x8 a[4], b[4];
#pragma unroll
    for (int mi = 0; mi < 4; mi++)
      a[mi] = *(const bf16x8*)&ldsA[cur][(row0 + mi * 16 + lr) * BK + lh * 8];
#pragma unroll
    for (int ni = 0; ni < 4; ni++)
      b[ni] = *(const bf16x8*)&ldsB[cur][(col0 + ni * 16 + lr) * BK + lh * 8];
#pragma unroll
    for (int mi = 0; mi < 4; mi++)
#pragma unroll
      for (int ni = 0; ni < 4; ni++)
        acc[mi][ni] = __builtin_amdgcn_mfma_f32_16x16x32_bf16(a[mi], b[ni], acc[mi][ni], 0, 0, 0);
    __syncthreads();
  }
#pragma unroll
  for (int mi = 0; mi < 4; mi++) {
    int row = m0 + row0 + mi * 16 + lh * 4;
#pragma unroll
    for (int ni = 0; ni < 4; ni++) {
      int col = n0 + col0 + ni * 16 + lr;
#pragma unroll
      for (int r = 0; r < 4; r++)
        Cout[(size_t)(row + r) * N + col] = acc[mi][ni][r];
    }
  }
}

// ---------------- bias + RoPE for q,k; writes bf16. K pre-swizzled (d ^= (s&15)<<3) ----------------
__global__ __launch_bounds__(256) void k_postproc(const float* __restrict__ Cq,
                                                  const float* __restrict__ qb,
                                                  const float* __restrict__ kb,
                                                  const float* __restrict__ cosb,
                                                  const float* __restrict__ sinb,
                                                  u16* __restrict__ Qo,
                                                  u16* __restrict__ Ko) {
  int s = blockIdx.x;
  int col = blockIdx.y * 256 + threadIdx.x;  // 0..4095 (q then k)
  int d = col & 127;
  float c = cosb[s * D_N + d], sn = sinb[s * D_N + d];
  const float* row = Cq + (size_t)s * NQKV;
  if (col < E_N) {
    float val = row[col] + qb[col];
    float other = (d < 64) ? -(row[col + 64] + qb[col + 64]) : (row[col - 64] + qb[col - 64]);
    int h = col >> 7;
    Qo[((size_t)h * S_N + s) * D_N + d] = f2bf(val * c + other * sn);
  } else {
    int cc = col - E_N;
    int kvh = cc >> 7;
    float val = row[col] + kb[cc];
    float other = (d < 64) ? -(row[col + 64] + kb[cc + 64]) : (row[col - 64] + kb[cc - 64]);
    int dsw = d ^ ((s & 15) << 3);  // pre-swizzle for bank-conflict-free ds_read_b128 (256B rows)
    Ko[((size_t)kvh * S_N + s) * D_N + dsw] = f2bf(val * c + other * sn);
  }
}

// ---------------- V: bias + transpose to [KVH*D][S] bf16, pre-swizzled ((s&127) ^= (d&15)<<3) ----------------
__global__ __launch_bounds__(256) void k_vt(const float* __restrict__ Cq,
                                            const float* __restrict__ vb,
                                            u16* __restrict__ Vt) {
  __shared__ float t[64][65];
  int s0 = blockIdx.x * 64, c0 = blockIdx.y * 64;  // c in 0..511 (= kvh*128+d)
  int lr = threadIdx.x >> 6, lc = threadIdx.x & 63;
  float bias = vb[c0 + lc];
#pragma unroll
  for (int i = 0; i < 64; i += 4)
    t[lr + i][lc] = Cq[(size_t)(s0 + lr + i) * NQKV + 4096 + c0 + lc] + bias;
  __syncthreads();
#pragma unroll
  for (int i = 0; i < 64; i += 4) {
    int cc = c0 + lr + i;
    int full = s0 + lc;
    int pos = (full & ~127) | ((full & 127) ^ ((cc & 15) << 3));
    Vt[(size_t)cc * S_N + pos] = f2bf(t[lc][lr + i]);
  }
}

// ---------------- flash attention, GQA, causal ----------------
// grid: (16 qtiles, 28 heads), block 256 (4 waves x 32 q-rows = 128 q/block)
// 32x32x16 MFMA, swapped QK^T (S^T: col=lane&31=q) -> lane-local softmax.
// KVBLK=128, single-buffered K/V (64KB LDS, 2 blocks/CU).
// P redistributed to PV B-fragments in-register via cvt_pk + permlane32_swap.
__global__ __launch_bounds__(256, 2) void k_attn(const u16* __restrict__ Q,
                                                 const u16* __restrict__ Kc,
                                                 const u16* __restrict__ Vt,
                                                 u16* __restrict__ Aout) {
  __shared__ __align__(16) u16 Klds[128 * 128];
  __shared__ __align__(16) u16 Vlds[128 * 128];
  const int h = blockIdx.y;
  const int kvh = h / 7;  // H/KVH = 7
  // heavy-first, and offset heads>=16 so the two co-resident blocks on a CU differ in size
  const int qt = (15 - blockIdx.x + ((blockIdx.y & 16) ? 8 : 0)) & 15;
  const int q0 = qt * 128;
  const int tid = threadIdx.x, w = tid >> 6, lane = tid & 63;
  const int l31 = lane & 31, hi = lane >> 5;
  const int hi8 = hi * 8;
  const int sw = (l31 & 15) << 3;  // element-xor for LDS reads (matches global pre-swizzle)
  const int qloc = w * 32 + l31;   // q row within block
  const int qrow = q0 + qloc;      // global q row

  // Q fragments (B operand): col=q=lane&31, k=d = dstep*16 + hi*8 + e
  bf16x8 qf[8];
  {
    const u16* qp = Q + ((size_t)h * S_N + qrow) * D_N + hi8;
#pragma unroll
    for (int dstep = 0; dstep < 8; ++dstep) qf[dstep] = *(const bf16x8*)(qp + dstep * 16);
  }

  f32x16 o[4];
#pragma unroll
  for (int i = 0; i < 4; i++)
#pragma unroll
    for (int r = 0; r < 16; r++) o[i][r] = 0.f;

  float m2 = -3.0e38f;   // running max, in exp2 domain (s * msc)
  float lsum = 0.f;      // per-lane partial (this lane's half of kv)
  const float msc = 0.12751743f;  // 1/sqrt(128) * log2(e)

  auto stageKV = [&](int t) {
    const u16* ks = Kc + ((size_t)kvh * S_N + t * 128) * D_N;  // tile is contiguous 32KB
#pragma unroll
    for (int j = 0; j < 8; ++j)
      gload16(ks + (j * 256 + tid) * 8, &Klds[(j * 256 + tid) * 8]);
    const u16* vs = Vt + (size_t)kvh * D_N * S_N + qt * 0 + 0;  // base of this kvh's Vt
#pragma unroll
    for (int j = 0; j < 8; ++j) {
      int row = j * 16 + (tid >> 4);
      gload16(vs + (size_t)row * S_N + t * 128 + (tid & 15) * 8,
              &Vlds[row * 128 + (tid & 15) * 8]);
    }
  };

  const int nt = qt + 1;
  for (int t = 0; t < nt; ++t) {
    __syncthreads();  // all waves done reading previous tile
    stageKV(t);
    __syncthreads();  // vmcnt(0) drain: tile resident + visible
    // ---- S^T = K @ Q^T : A=K rows=kv, B=Q cols=q ----
    f32x16 sacc[4];
#pragma unroll
    for (int i = 0; i < 4; i++)
#pragma unroll
      for (int r = 0; r < 16; r++) sacc[i][r] = 0.f;
    __builtin_amdgcn_s_setprio(1);
#pragma unroll
    for (int dstep = 0; dstep < 8; ++dstep)
#pragma unroll
      for (int ksub = 0; ksub < 4; ++ksub) {
        bf16x8 ka = *(const bf16x8*)&Klds[(ksub * 32 + l31) * D_N + ((dstep * 16 + hi8) ^ sw)];
        sacc[ksub] = __builtin_amdgcn_mfma_f32_32x32x16_bf16(ka, qf[dstep], sacc[ksub], 0, 0, 0);
      }
    __builtin_amdgcn_s_setprio(0);
    // ---- scale to exp2 domain (+ causal mask on diagonal tile) ----
    if (t == qt) {
#pragma unroll
      for (int ksub = 0; ksub < 4; ++ksub)
#pragma unroll
        for (int r = 0; r < 16; ++r) {
          int kvloc = ksub * 32 + (r & 3) + 8 * (r >> 2) + 4 * hi;
          sacc[ksub][r] = (kvloc <= qloc) ? sacc[ksub][r] * msc : -3.0e38f;
        }
    } else {
#pragma unroll
      for (int ksub = 0; ksub < 4; ++ksub)
#pragma unroll
        for (int r = 0; r < 16; ++r) sacc[ksub][r] *= msc;
    }
    // ---- lane-local max (single cross-lane op: xor-32) ----
    float tmax = fmaxf(fmaxf(vmax16(sacc[0]), vmax16(sacc[1])),
                       fmaxf(vmax16(sacc[2]), vmax16(sacc[3])));
    tmax = fmaxf(tmax, __shfl_xor(tmax, 32));
    // ---- defer-max (T13): rescale only if max grew past threshold ----
    if (__any(tmax > m2 + 8.0f)) {
      float m2new = fmaxf(m2, tmax);
      float scl = __builtin_amdgcn_exp2f(m2 - m2new);
#pragma unroll
      for (int i = 0; i < 4; i++)
#pragma unroll
        for (int r = 0; r < 16; r++) o[i][r] *= scl;
      lsum *= scl;
      m2 = m2new;
    }
    // ---- p = exp2(y - m2), in place; accumulate lane-partial sum ----
#pragma unroll
    for (int ksub = 0; ksub < 4; ++ksub) {
#pragma unroll
      for (int r = 0; r < 16; ++r)
        sacc[ksub][r] = __builtin_amdgcn_exp2f(sacc[ksub][r] - m2);
      lsum += vsum16(sacc[ksub]);
    }
    // ---- PV: O^T[d][q] += Vt[d][kv] * P^T[kv][q] ----
    __builtin_amdgcn_s_setprio(1);
#pragma unroll
    for (int ksub = 0; ksub < 4; ++ksub) {
      // pack p into bf16 words: w_i = kv-local pair (own lane's rows)
      u32 pw[8];
#pragma unroll
      for (int i = 0; i < 8; ++i) pw[i] = cvt_pk_bf16(sacc[ksub][2 * i], sacc[ksub][2 * i + 1]);
      // redistribute across the lane/lane+32 split (4 swaps -> both frag halves)
      pl32swap(pw[0], pw[2]);
      pl32swap(pw[1], pw[3]);
      pl32swap(pw[4], pw[6]);
      pl32swap(pw[5], pw[7]);
#pragma unroll
      for (int j = 0; j < 2; ++j) {
        u32x4 fw = {pw[j * 4 + 0], pw[j * 4 + 1], pw[j * 4 + 2], pw[j * 4 + 3]};
        bf16x8 pb = __builtin_bit_cast(bf16x8, fw);
#pragma unroll
        for (int dsub = 0; dsub < 4; ++dsub) {
          bf16x8 va =
              *(const bf16x8*)&Vlds[(dsub * 32 + l31) * 128 + ((ksub * 32 + j * 16 + hi8) ^ sw)];
          o[dsub] = __builtin_amdgcn_mfma_f32_32x32x16_bf16(va, pb, o[dsub], 0, 0, 0);
        }
      }
    }
    __builtin_amdgcn_s_setprio(0);
  }
  // ---- epilogue: finish sum across the two kv-halves, normalize, store ----
  float lt = lsum + __shfl_xor(lsum, 32);
  float ri = 1.0f / lt;
  u16* op = Aout + (size_t)qrow * E_N + h * D_N;
#pragma unroll
  for (int dsub = 0; dsub < 4; ++dsub)
#pragma unroll
    for (int g = 0; g < 4; ++g) {
      int dbase = dsub * 32 + 8 * g + 4 * hi;
      u32x2 wv;
      wv[0] = (u32)f2bf(o[dsub][g * 4 + 0] * ri) | ((u32)f2bf(o[dsub][g * 4 + 1] * ri) << 16);
      wv[1] = (u32)f2bf(o[dsub][g * 4 + 2] * ri) | ((u32)f2bf(o[dsub][g * 4 + 3] * ri) << 16);
      *(u32x2*)(op + dbase) = wv;
    }
}

extern "C" void kernel_launch(void* const* d_in, const int* in_sizes, int n_in,
                              void* d_out, int out_size, void* d_ws, size_t ws_size,
                              hipStream_t stream) {
  const float* hs   = (const float*)d_in[0];
  const float* cosb = (const float*)d_in[1];
  const float* sinb = (const float*)d_in[2];
  // d_in[3] = attn_mask (always causal tril — applied analytically)
  const float* qw = (const float*)d_in[4];
  const float* qb = (const float*)d_in[5];
  const float* kw = (const float*)d_in[6];
  const float* kb = (const float*)d_in[7];
  const float* vw = (const float*)d_in[8];
  const float* vb = (const float*)d_in[9];
  const float* ow = (const float*)d_in[10];
  float* outp = (float*)d_out;

  char* ws = (char*)d_ws;
  u16* hsb    = (u16*)(ws);                                   // 2048x3584 bf16
  u16* wt     = (u16*)(ws + 14680064);                        // 4608x3584 bf16 (later reused for ow^T)
  float* qkv  = (float*)(ws + 14680064 + 33030144);           // 2048x4608 f32
  u16* attn_o = (u16*)qkv;                                    // reuse region after postproc
  char* p2 = ws + 14680064 + 33030144 + 37748736;
  u16* Qb  = (u16*)p2;                                        // [28][2048][128]
  u16* Kb  = (u16*)(p2 + 14680064);                           // [4][2048][128] (swizzled)
  u16* Vtb = (u16*)(p2 + 14680064 + 2097152);                 // [512][2048] (swizzled)

  // 1. hs -> bf16
  k_f32_to_bf16<<<dim3(7340032 / 8 / 256), dim3(256), 0, stream>>>(hs, hsb, 7340032 / 8);
  // 2-4. weight transposes -> wt (q|k|v rows)
  k_transpose_bf16<<<dim3(3584 / 64, 3584 / 64), dim3(256), 0, stream>>>(qw, wt, 3584, 3584);
  k_transpose_bf16<<<dim3(512 / 64, 3584 / 64), dim3(256), 0, stream>>>(kw, wt + (size_t)3584 * 3584, 3584, 512);
  k_transpose_bf16<<<dim3(512 / 64, 3584 / 64), dim3(256), 0, stream>>>(vw, wt + (size_t)4096 * 3584, 3584, 512);
  // 5. QKV GEMM
  k_gemm_bt<<<dim3(4608 / 128, 2048 / 128), dim3(256), 0, stream>>>(hsb, wt, qkv, 2048, 4608, 3584);
  // 6. bias + RoPE -> Q,K bf16
  k_postproc<<<dim3(2048, 16), dim3(256), 0, stream>>>(qkv, qb, kb, cosb, sinb, Qb, Kb);
  // 7. V bias + transpose
  k_vt<<<dim3(32, 8), dim3(256), 0, stream>>>(qkv, vb, Vtb);
  // 8. ow transpose (into wt region — gemm1 already consumed it)
  k_transpose_bf16<<<dim3(3584 / 64, 3584 / 64), dim3(256), 0, stream>>>(ow, wt, 3584, 3584);
  // 9. attention -> attn_o (bf16, aliases qkv region)
  k_attn<<<dim3(16, 28), dim3(256), 0, stream>>>(Qb, Kb, Vtb, attn_o);
  // 10. output projection -> d_out (f32)
  k_gemm_bt<<<dim3(3584 / 128, 2048 / 128), dim3(256), 0, stream>>>(attn_o, wt, outp, 2048, 3584, 3584);
}

// Round 4
// 300.932 us; speedup vs baseline: 1.2394x; 1.0351x over previous
//
#include <hip/hip_runtime.h>

#define H_N 28
#define KVH_N 4
#define D_N 128
#define S_N 2048
#define E_N 3584
#define NQKV 4608

typedef unsigned short u16;
typedef unsigned int u32;
typedef __bf16 bf16x8 __attribute__((ext_vector_type(8)));
typedef float f32x4 __attribute__((ext_vector_type(4)));
typedef float f32x16 __attribute__((ext_vector_type(16)));
typedef unsigned short u16x8 __attribute__((ext_vector_type(8)));
typedef unsigned int u32x2 __attribute__((ext_vector_type(2)));
typedef unsigned int u32x4 __attribute__((ext_vector_type(4)));

typedef __attribute__((address_space(1))) void gvoid_t;
typedef __attribute__((address_space(3))) void lvoid_t;

static __device__ __forceinline__ u16 f2bf(float f) {
  __bf16 h = (__bf16)f;
  return __builtin_bit_cast(unsigned short, h);
}

static __device__ __forceinline__ void gload16(const void* g, void* l) {
  __builtin_amdgcn_global_load_lds((gvoid_t*)g, (lvoid_t*)l, 16, 0, 0);
}

static __device__ __forceinline__ u32 cvt_pk_bf16(float lo, float hi) {
  u32 r;
  asm("v_cvt_pk_bf16_f32 %0, %1, %2" : "=v"(r) : "v"(lo), "v"(hi));
  return r;
}

static __device__ __forceinline__ void pl32swap(u32& a, u32& b) {
  asm volatile("v_permlane32_swap_b32 %0, %1" : "+v"(a), "+v"(b));
}

static __device__ __forceinline__ float vmax16(f32x16 v) {
  float a = fmaxf(fmaxf(v[0], v[1]), fmaxf(v[2], v[3]));
  float b = fmaxf(fmaxf(v[4], v[5]), fmaxf(v[6], v[7]));
  float c = fmaxf(fmaxf(v[8], v[9]), fmaxf(v[10], v[11]));
  float d = fmaxf(fmaxf(v[12], v[13]), fmaxf(v[14], v[15]));
  return fmaxf(fmaxf(a, b), fmaxf(c, d));
}

static __device__ __forceinline__ float vsum16(f32x16 v) {
  float a = (v[0] + v[1]) + (v[2] + v[3]);
  float b = (v[4] + v[5]) + (v[6] + v[7]);
  float c = (v[8] + v[9]) + (v[10] + v[11]);
  float d = (v[12] + v[13]) + (v[14] + v[15]);
  return (a + b) + (c + d);
}

// ---------------- hs f32 -> bf16, GEMM-swizzled (8-elem group ^= row&7) ----------------
__global__ __launch_bounds__(256) void k_hs_bf16_swz(const float* __restrict__ in,
                                                     u16* __restrict__ out) {
  int g = blockIdx.x * 256 + threadIdx.x;  // 2048*3584/8 groups
  int row = g / 448, c8 = g % 448;
  const float4* p = (const float4*)(in + (size_t)g * 8);
  float4 a = p[0], b = p[1];
  u16x8 r;
  r[0] = f2bf(a.x); r[1] = f2bf(a.y); r[2] = f2bf(a.z); r[3] = f2bf(a.w);
  r[4] = f2bf(b.x); r[5] = f2bf(b.y); r[6] = f2bf(b.z); r[7] = f2bf(b.w);
  int dc8 = c8 ^ (row & 7);
  *(u16x8*)(out + (size_t)row * E_N + dc8 * 8) = r;
}

// ---------------- transpose f32 [R][C] -> bf16 [C][R], GEMM-swizzled rows ----------------
__global__ __launch_bounds__(256) void k_transpose_bf16(const float* __restrict__ in,
                                                        u16* __restrict__ out,
                                                        int R, int C) {
  __shared__ float t[64][65];
  int r0 = blockIdx.y * 64, c0 = blockIdx.x * 64;
  int lr = threadIdx.x >> 6, lc = threadIdx.x & 63;
#pragma unroll
  for (int i = 0; i < 64; i += 4)
    t[lr + i][lc] = in[(size_t)(r0 + lr + i) * C + c0 + lc];
  __syncthreads();
#pragma unroll
  for (int i = 0; i < 64; i += 4) {
    int orow = c0 + lr + i;
    int sw = (orow & 7) << 3;
    out[(size_t)orow * R + r0 + (lc ^ sw)] = f2bf(t[lc][lr + i]);
  }
}

// ---------------- GEMM 128x256 tile, BK=64, 8 waves, 4-phase counted-vmcnt pipeline ----
// A[M,K], Bt[N,K] both bf16 pre-swizzled (col ^= (row&7)<<3 per 64-elem span).
// C f32 linear. Grid = (M/128)*(N/256), %8==0 for XCD swizzle.
#define VM6 asm volatile("s_waitcnt vmcnt(6)" ::: "memory")
#define VM0 asm volatile("s_waitcnt vmcnt(0)" ::: "memory")

#define GPHASE(BUF, Q, STAGES, VMW)                                                              \
  {                                                                                              \
    STAGES                                                                                       \
    VMW                                                                                          \
    bf16x8 af[2][2];                                                                             \
    _Pragma("unroll") for (int dm = 0; dm < 2; ++dm) {                                           \
      _Pragma("unroll") for (int kk = 0; kk < 2; ++kk)                                           \
          af[dm][kk] = *(const bf16x8*)&L[BUF][(wr * 64 + ((Q)*2 + dm) * 16 + lr) * 64 +         \
                                              ((kk * 32 + lh8) ^ swz)];                          \
    }                                                                                            \
    if ((Q) == 0) {                                                                              \
      _Pragma("unroll") for (int ni = 0; ni < 4; ++ni) {                                         \
        _Pragma("unroll") for (int kk = 0; kk < 2; ++kk)                                         \
            bfr[ni][kk] = *(const bf16x8*)&L[BUF][(128 + wc * 64 + ni * 16 + lr) * 64 +          \
                                                  ((kk * 32 + lh8) ^ swz)];                      \
      }                                                                                          \
    }                                                                                            \
    __builtin_amdgcn_s_barrier();                                                                \
    __builtin_amdgcn_s_setprio(1);                                                               \
    _Pragma("unroll") for (int dm = 0; dm < 2; ++dm) {                                           \
      _Pragma("unroll") for (int ni = 0; ni < 4; ++ni) {                                         \
        _Pragma("unroll") for (int kk = 0; kk < 2; ++kk)                                         \
            acc[(Q)*2 + dm][ni] = __builtin_amdgcn_mfma_f32_16x16x32_bf16(                       \
                af[dm][kk], bfr[ni][kk], acc[(Q)*2 + dm][ni], 0, 0, 0);                          \
      }                                                                                          \
    }                                                                                            \
    __builtin_amdgcn_s_setprio(0);                                                               \
    __builtin_amdgcn_s_barrier();                                                                \
  }

__global__ __launch_bounds__(512, 2) void k_gemm256(const u16* __restrict__ A,
                                                    const u16* __restrict__ Bt,
                                                    float* __restrict__ Cout,
                                                    int Nn, int nxt) {
  __shared__ __align__(16) u16 L[2][384 * 64];  // rows 0-127: A, 128-383: B  (96KB)
  const int K = 3584;
  const int tid = threadIdx.x;
  const int lane = tid & 63;
  const int w = tid >> 6;
  const int lr = lane & 15, lh = lane >> 4, lh8 = lh * 8;
  const int swz = (lr & 7) << 3;
  const int wr = w >> 2, wc = w & 3;

  const int nwg = gridDim.x;
  const int bid = blockIdx.x;
  const int lb = (bid & 7) * (nwg >> 3) + (bid >> 3);  // XCD-contiguous chunks
  const int mt = lb / nxt, nt = lb % nxt;
  const size_t m0 = (size_t)mt << 7;
  const size_t n0 = (size_t)nt << 8;

  const u16* Abase = A + m0 * K;
  const u16* Bbase = Bt + n0 * K;

  // stage one 8KB chunk: ck 0,1 = A rows [ck*64,+64); ck 2..5 = B rows [(ck-2)*64,+64)
  auto stageC = [&](int buf, int ck, int kt) {
    const u16* src = (ck < 2) ? (Abase + (size_t)(ck * 64 + (tid >> 3)) * K)
                              : (Bbase + (size_t)((ck - 2) * 64 + (tid >> 3)) * K);
    gload16(src + kt * 64 + (tid & 7) * 8, &L[buf][(ck * 64 + (tid >> 3)) * 64 + (tid & 7) * 8]);
  };

  f32x4 acc[4][4];
  const f32x4 z = {0.f, 0.f, 0.f, 0.f};
#pragma unroll
  for (int i = 0; i < 4; i++)
#pragma unroll
    for (int j = 0; j < 4; j++) acc[i][j] = z;
  bf16x8 bfr[4][2];

  const int nkt2 = K / 128;  // 28 iterations, 2 K-tiles each

  // prologue: kt0 full -> buf0; kt1.b0,b1,b2 -> buf1; drain
#pragma unroll
  for (int ck = 0; ck < 6; ++ck) stageC(0, ck, 0);
  stageC(1, 2, 1);
  stageC(1, 3, 1);
  stageC(1, 4, 1);
  __syncthreads();

  for (int i = 0; i + 1 < nkt2; ++i) {
    const int kt1 = 2 * i + 1, kt2 = 2 * i + 2, kt3 = 2 * i + 3;
    GPHASE(0, 0, { stageC(1, 0, kt1); stageC(1, 1, kt1); stageC(1, 5, kt1); }, VM6;)
    GPHASE(0, 1, { stageC(0, 2, kt2); stageC(0, 3, kt2); stageC(0, 4, kt2); }, ;)
    GPHASE(1, 0, { stageC(0, 5, kt2); stageC(0, 0, kt2); stageC(0, 1, kt2); }, VM6;)
    GPHASE(1, 1, { stageC(1, 2, kt3); stageC(1, 3, kt3); stageC(1, 4, kt3); }, ;)
  }
  {  // peeled last iteration
    const int kt1 = 2 * (nkt2 - 1) + 1;
    GPHASE(0, 0, { stageC(1, 0, kt1); stageC(1, 1, kt1); stageC(1, 5, kt1); }, VM6;)
    GPHASE(0, 1, { ; }, ;)
    GPHASE(1, 0, { ; }, VM0;)
    GPHASE(1, 1, { ; }, ;)
  }

  const size_t Nsz = (size_t)Nn;
#pragma unroll
  for (int mi = 0; mi < 4; mi++) {
    size_t row = m0 + wr * 64 + mi * 16 + lh * 4;
#pragma unroll
    for (int ni = 0; ni < 4; ni++) {
      size_t col = n0 + wc * 64 + ni * 16 + lr;
#pragma unroll
      for (int r = 0; r < 4; r++) Cout[(row + r) * Nsz + col] = acc[mi][ni][r];
    }
  }
}

// ---------------- bias + RoPE for q,k; writes bf16. K pre-swizzled (d ^= (s&15)<<3) ----------------
__global__ __launch_bounds__(256) void k_postproc(const float* __restrict__ Cq,
                                                  const float* __restrict__ qb,
                                                  const float* __restrict__ kb,
                                                  const float* __restrict__ cosb,
                                                  const float* __restrict__ sinb,
                                                  u16* __restrict__ Qo,
                                                  u16* __restrict__ Ko) {
  int s = blockIdx.x;
  int col = blockIdx.y * 256 + threadIdx.x;  // 0..4095 (q then k)
  int d = col & 127;
  float c = cosb[s * D_N + d], sn = sinb[s * D_N + d];
  const float* row = Cq + (size_t)s * NQKV;
  if (col < E_N) {
    float val = row[col] + qb[col];
    float other = (d < 64) ? -(row[col + 64] + qb[col + 64]) : (row[col - 64] + qb[col - 64]);
    int h = col >> 7;
    Qo[((size_t)h * S_N + s) * D_N + d] = f2bf(val * c + other * sn);
  } else {
    int cc = col - E_N;
    int kvh = cc >> 7;
    float val = row[col] + kb[cc];
    float other = (d < 64) ? -(row[col + 64] + kb[cc + 64]) : (row[col - 64] + kb[cc - 64]);
    int dsw = d ^ ((s & 15) << 3);  // attn-LDS pre-swizzle
    Ko[((size_t)kvh * S_N + s) * D_N + dsw] = f2bf(val * c + other * sn);
  }
}

// ---------------- V: bias + transpose to [KVH*D][S] bf16, attn pre-swizzled ----------------
__global__ __launch_bounds__(256) void k_vt(const float* __restrict__ Cq,
                                            const float* __restrict__ vb,
                                            u16* __restrict__ Vt) {
  __shared__ float t[64][65];
  int s0 = blockIdx.x * 64, c0 = blockIdx.y * 64;  // c in 0..511 (= kvh*128+d)
  int lr = threadIdx.x >> 6, lc = threadIdx.x & 63;
  float bias = vb[c0 + lc];
#pragma unroll
  for (int i = 0; i < 64; i += 4)
    t[lr + i][lc] = Cq[(size_t)(s0 + lr + i) * NQKV + 4096 + c0 + lc] + bias;
  __syncthreads();
#pragma unroll
  for (int i = 0; i < 64; i += 4) {
    int cc = c0 + lr + i;
    int full = s0 + lc;
    int pos = (full & ~127) | ((full & 127) ^ ((cc & 15) << 3));
    Vt[(size_t)cc * S_N + pos] = f2bf(t[lc][lr + i]);
  }
}

// ---------------- flash attention, GQA, causal (round-3 structure) ----------------
// Output written GEMM-pre-swizzled (col ^= (qrow&7)<<3) for k_gemm256's A operand.
__global__ __launch_bounds__(256, 2) void k_attn(const u16* __restrict__ Q,
                                                 const u16* __restrict__ Kc,
                                                 const u16* __restrict__ Vt,
                                                 u16* __restrict__ Aout) {
  __shared__ __align__(16) u16 Klds[128 * 128];
  __shared__ __align__(16) u16 Vlds[128 * 128];
  const int h = blockIdx.y;
  const int kvh = h / 7;  // H/KVH = 7
  const int qt = (15 - blockIdx.x + ((blockIdx.y & 16) ? 8 : 0)) & 15;
  const int q0 = qt * 128;
  const int tid = threadIdx.x, w = tid >> 6, lane = tid & 63;
  const int l31 = lane & 31, hi = lane >> 5;
  const int hi8 = hi * 8;
  const int sw = (l31 & 15) << 3;
  const int qloc = w * 32 + l31;
  const int qrow = q0 + qloc;

  bf16x8 qf[8];
  {
    const u16* qp = Q + ((size_t)h * S_N + qrow) * D_N + hi8;
#pragma unroll
    for (int dstep = 0; dstep < 8; ++dstep) qf[dstep] = *(const bf16x8*)(qp + dstep * 16);
  }

  f32x16 o[4];
#pragma unroll
  for (int i = 0; i < 4; i++)
#pragma unroll
    for (int r = 0; r < 16; r++) o[i][r] = 0.f;

  float m2 = -3.0e38f;
  float lsum = 0.f;
  const float msc = 0.12751743f;  // 1/sqrt(128) * log2(e)

  auto stageKV = [&](int t) {
    const u16* ks = Kc + ((size_t)kvh * S_N + t * 128) * D_N;
#pragma unroll
    for (int j = 0; j < 8; ++j)
      gload16(ks + (j * 256 + tid) * 8, &Klds[(j * 256 + tid) * 8]);
    const u16* vs = Vt + (size_t)kvh * D_N * S_N;
#pragma unroll
    for (int j = 0; j < 8; ++j) {
      int row = j * 16 + (tid >> 4);
      gload16(vs + (size_t)row * S_N + t * 128 + (tid & 15) * 8,
              &Vlds[row * 128 + (tid & 15) * 8]);
    }
  };

  const int nt = qt + 1;
  for (int t = 0; t < nt; ++t) {
    __syncthreads();
    stageKV(t);
    __syncthreads();
    f32x16 sacc[4];
#pragma unroll
    for (int i = 0; i < 4; i++)
#pragma unroll
      for (int r = 0; r < 16; r++) sacc[i][r] = 0.f;
    __builtin_amdgcn_s_setprio(1);
#pragma unroll
    for (int dstep = 0; dstep < 8; ++dstep)
#pragma unroll
      for (int ksub = 0; ksub < 4; ++ksub) {
        bf16x8 ka = *(const bf16x8*)&Klds[(ksub * 32 + l31) * D_N + ((dstep * 16 + hi8) ^ sw)];
        sacc[ksub] = __builtin_amdgcn_mfma_f32_32x32x16_bf16(ka, qf[dstep], sacc[ksub], 0, 0, 0);
      }
    __builtin_amdgcn_s_setprio(0);
    if (t == qt) {
#pragma unroll
      for (int ksub = 0; ksub < 4; ++ksub)
#pragma unroll
        for (int r = 0; r < 16; ++r) {
          int kvloc = ksub * 32 + (r & 3) + 8 * (r >> 2) + 4 * hi;
          sacc[ksub][r] = (kvloc <= qloc) ? sacc[ksub][r] * msc : -3.0e38f;
        }
    } else {
#pragma unroll
      for (int ksub = 0; ksub < 4; ++ksub)
#pragma unroll
        for (int r = 0; r < 16; ++r) sacc[ksub][r] *= msc;
    }
    float tmax = fmaxf(fmaxf(vmax16(sacc[0]), vmax16(sacc[1])),
                       fmaxf(vmax16(sacc[2]), vmax16(sacc[3])));
    tmax = fmaxf(tmax, __shfl_xor(tmax, 32));
    if (__any(tmax > m2 + 8.0f)) {
      float m2new = fmaxf(m2, tmax);
      float scl = __builtin_amdgcn_exp2f(m2 - m2new);
#pragma unroll
      for (int i = 0; i < 4; i++)
#pragma unroll
        for (int r = 0; r < 16; r++) o[i][r] *= scl;
      lsum *= scl;
      m2 = m2new;
    }
#pragma unroll
    for (int ksub = 0; ksub < 4; ++ksub) {
#pragma unroll
      for (int r = 0; r < 16; ++r)
        sacc[ksub][r] = __builtin_amdgcn_exp2f(sacc[ksub][r] - m2);
      lsum += vsum16(sacc[ksub]);
    }
    __builtin_amdgcn_s_setprio(1);
#pragma unroll
    for (int ksub = 0; ksub < 4; ++ksub) {
      u32 pw[8];
#pragma unroll
      for (int i = 0; i < 8; ++i) pw[i] = cvt_pk_bf16(sacc[ksub][2 * i], sacc[ksub][2 * i + 1]);
      pl32swap(pw[0], pw[2]);
      pl32swap(pw[1], pw[3]);
      pl32swap(pw[4], pw[6]);
      pl32swap(pw[5], pw[7]);
#pragma unroll
      for (int j = 0; j < 2; ++j) {
        u32x4 fw = {pw[j * 4 + 0], pw[j * 4 + 1], pw[j * 4 + 2], pw[j * 4 + 3]};
        bf16x8 pb = __builtin_bit_cast(bf16x8, fw);
#pragma unroll
        for (int dsub = 0; dsub < 4; ++dsub) {
          bf16x8 va =
              *(const bf16x8*)&Vlds[(dsub * 32 + l31) * 128 + ((ksub * 32 + j * 16 + hi8) ^ sw)];
          o[dsub] = __builtin_amdgcn_mfma_f32_32x32x16_bf16(va, pb, o[dsub], 0, 0, 0);
        }
      }
    }
    __builtin_amdgcn_s_setprio(0);
  }
  float lt = lsum + __shfl_xor(lsum, 32);
  float ri = 1.0f / lt;
  u16* op = Aout + (size_t)qrow * E_N + h * D_N;
  const int sw2 = (qrow & 7) << 3;  // GEMM-A pre-swizzle
#pragma unroll
  for (int dsub = 0; dsub < 4; ++dsub)
#pragma unroll
    for (int g = 0; g < 4; ++g) {
      int dbase = dsub * 32 + 8 * g + 4 * hi;
      u32x2 wv;
      wv[0] = (u32)f2bf(o[dsub][g * 4 + 0] * ri) | ((u32)f2bf(o[dsub][g * 4 + 1] * ri) << 16);
      wv[1] = (u32)f2bf(o[dsub][g * 4 + 2] * ri) | ((u32)f2bf(o[dsub][g * 4 + 3] * ri) << 16);
      *(u32x2*)(op + (dbase ^ sw2)) = wv;
    }
}

extern "C" void kernel_launch(void* const* d_in, const int* in_sizes, int n_in,
                              void* d_out, int out_size, void* d_ws, size_t ws_size,
                              hipStream_t stream) {
  const float* hs   = (const float*)d_in[0];
  const float* cosb = (const float*)d_in[1];
  const float* sinb = (const float*)d_in[2];
  // d_in[3] = attn_mask (causal tril — applied analytically)
  const float* qw = (const float*)d_in[4];
  const float* qb = (const float*)d_in[5];
  const float* kw = (const float*)d_in[6];
  const float* kb = (const float*)d_in[7];
  const float* vw = (const float*)d_in[8];
  const float* vb = (const float*)d_in[9];
  const float* ow = (const float*)d_in[10];
  float* outp = (float*)d_out;

  char* ws = (char*)d_ws;
  u16* hsb    = (u16*)(ws);                                   // 2048x3584 bf16 (swz)
  u16* wt     = (u16*)(ws + 14680064);                        // 4608x3584 bf16 (swz; later ow^T)
  float* qkv  = (float*)(ws + 14680064 + 33030144);           // 2048x4608 f32
  u16* attn_o = (u16*)qkv;                                    // reuse region after postproc
  char* p2 = ws + 14680064 + 33030144 + 37748736;
  u16* Qb  = (u16*)p2;                                        // [28][2048][128]
  u16* Kb  = (u16*)(p2 + 14680064);                           // [4][2048][128] (attn swz)
  u16* Vtb = (u16*)(p2 + 14680064 + 2097152);                 // [512][2048] (attn swz)

  // 1. hs -> bf16 (GEMM-swizzled)
  k_hs_bf16_swz<<<dim3(917504 / 256), dim3(256), 0, stream>>>(hs, hsb);
  // 2-4. weight transposes -> wt (q|k|v rows, GEMM-swizzled)
  k_transpose_bf16<<<dim3(3584 / 64, 3584 / 64), dim3(256), 0, stream>>>(qw, wt, 3584, 3584);
  k_transpose_bf16<<<dim3(512 / 64, 3584 / 64), dim3(256), 0, stream>>>(kw, wt + (size_t)3584 * 3584, 3584, 512);
  k_transpose_bf16<<<dim3(512 / 64, 3584 / 64), dim3(256), 0, stream>>>(vw, wt + (size_t)4096 * 3584, 3584, 512);
  // 5. QKV GEMM (M=2048, N=4608): 16x18 tiles = 288 blocks
  k_gemm256<<<dim3(288), dim3(512), 0, stream>>>(hsb, wt, qkv, 4608, 18);
  // 6. bias + RoPE -> Q,K bf16
  k_postproc<<<dim3(2048, 16), dim3(256), 0, stream>>>(qkv, qb, kb, cosb, sinb, Qb, Kb);
  // 7. V bias + transpose
  k_vt<<<dim3(32, 8), dim3(256), 0, stream>>>(qkv, vb, Vtb);
  // 8. ow transpose (into wt region — gemm1 already consumed it)
  k_transpose_bf16<<<dim3(3584 / 64, 3584 / 64), dim3(256), 0, stream>>>(ow, wt, 3584, 3584);
  // 9. attention -> attn_o (bf16, GEMM-swizzled, aliases qkv region)
  k_attn<<<dim3(16, 28), dim3(256), 0, stream>>>(Qb, Kb, Vtb, attn_o);
  // 10. output projection (M=2048, N=3584): 16x14 tiles = 224 blocks
  k_gemm256<<<dim3(224), dim3(512), 0, stream>>>(attn_o, wt, outp, 3584, 14);
}